// Round 9
// baseline (340.801 us; speedup 1.0000x reference)
//
#include <hip/hip_runtime.h>
#include <hip/hip_bf16.h>
#include <math.h>

typedef __hip_bfloat16 bf16;
typedef __attribute__((ext_vector_type(8))) short short8;
typedef __attribute__((ext_vector_type(4))) short short4v;
typedef __attribute__((ext_vector_type(4))) float float4v;

static constexpr int cB  = 2;
static constexpr int cC  = 128;
static constexpr int cH  = 128;
static constexpr int cW  = 128;
static constexpr int cP  = cH * cW;       // 16384
static constexpr int cC3 = 384;
static constexpr int cHID = 340;
static constexpr int cNW = 1024;
static constexpr float cEPS = 1e-6f;

__device__ __forceinline__ float bfu2f(unsigned short u){
  union { unsigned int i; float f; } c; c.i = ((unsigned int)u) << 16; return c.f;
}
__device__ __forceinline__ unsigned short f2b(float f){
  union { float f; unsigned int u; } c; c.f = f;
  unsigned int r = c.u + 0x7FFFu + ((c.u >> 16) & 1u);
  return (unsigned short)(r >> 16);
}

// ---- convert all 8 weight matrices fp32 -> bf16 (with padding) into WB; tail zeroes S
__global__ void k_wcvt(const float* __restrict__ qkv_s, const float* __restrict__ qkv_c,
                       const float* __restrict__ fin_s, const float* __restrict__ fin_c,
                       const float* __restrict__ prj_s, const float* __restrict__ prj_c,
                       const float* __restrict__ fo_s,  const float* __restrict__ fo_c,
                       unsigned short* __restrict__ WB, float* __restrict__ S){
  int i = blockIdx.x * 256 + threadIdx.x;
  if (i >= 319488){
    int j = i - 319488;
    if (j < 8704) S[j] = 0.f;
    return;
  }
  float v;
  if (i < 98304){
    v = (i < 49152) ? qkv_s[i] : qkv_c[i - 49152];
  } else if (i < 196608){
    int j = (i < 147456) ? (i - 98304) : (i - 147456);
    int row = j >> 7, col = j & 127;
    const float* src = (i < 147456) ? fin_s : fin_c;
    v = (row < cHID) ? src[row * 128 + col] : 0.f;
  } else if (i < 229376){
    v = (i < 212992) ? prj_s[i - 196608] : prj_c[i - 212992];
  } else {
    int j = (i < 274432) ? (i - 229376) : (i - 274432);
    int row = j / 352, col = j - row * 352;
    const float* src = (i < 274432) ? fo_s : fo_c;
    v = (col < cHID) ? src[row * cHID + col] : 0.f;
  }
  WB[i] = f2b(v);
}

// ---- fused LN + roll + QKV GEMM (spatial branch entry) ----
__global__ void __launch_bounds__(256) k_gemmLN(const unsigned short* __restrict__ Wb,
                                                const float* __restrict__ Xf,
                                                const float* __restrict__ gamma,
                                                const float* __restrict__ beta,
                                                unsigned short* __restrict__ Out){
  __shared__ short Xls[64 * 136];
  __shared__ short Wls[128 * 40];
  __shared__ float gls[128], bls[128];
  __shared__ float psum[64], pssq[64];
  int bid = blockIdx.x;
  int s  = (bid & 7) * 192 + (bid >> 3);
  int mt = s % 3;
  int r3 = s / 3;
  int pt = r3 & 255;
  int b  = r3 >> 8;
  int p0 = pt * 64;
  int m0 = mt * 128;
  int t  = threadIdx.x;
  int px = t & 63, cq = t >> 6;
  if (t < 64){ psum[t] = 0.f; pssq[t] = 0.f; }
  if (t < 128){ gls[t] = gamma[t]; bls[t] = beta[t]; }
  int rh = p0 >> 7, w0 = p0 & 127;
  int hs = (rh + 2) & (cH - 1);
  int sp = hs * cW + ((w0 + 2 + px) & (cW - 1));
  const float* xb = Xf + (size_t)b * cC * cP + sp;
  float xr[32];
  float s1 = 0.f, s2 = 0.f;
  #pragma unroll
  for (int j = 0; j < 32; j++){
    float v = xb[(size_t)(cq * 32 + j) * cP];
    xr[j] = v; s1 += v; s2 += v * v;
  }
  __syncthreads();
  atomicAdd(&psum[px], s1);
  atomicAdd(&pssq[px], s2);
  __syncthreads();
  float mean = psum[px] * (1.f / cC);
  float var  = pssq[px] * (1.f / cC) - mean * mean;
  float rstd = rsqrtf(var + cEPS);
  #pragma unroll
  for (int k = 0; k < 4; k++){
    short8 tv;
    #pragma unroll
    for (int e = 0; e < 8; e++){
      int c = cq * 32 + k * 8 + e;
      tv[e] = (short)f2b((xr[k * 8 + e] - mean) * rstd * gls[c] + bls[c]);
    }
    *(short8*)&Xls[px * 136 + cq * 32 + k * 8] = tv;
  }
  int lanelo = t & 15;
  int quad   = (t >> 4) & 3;
  int wv = t >> 6;
  int w1 = wv & 1;
  int w2 = wv >> 1;
  int srw = t >> 1;
  int kow = (t & 1) * 16;
  float4v acc[2][4];
  #pragma unroll
  for (int i = 0; i < 2; i++)
    #pragma unroll
    for (int j = 0; j < 4; j++)
      acc[i][j] = (float4v){0.f, 0.f, 0.f, 0.f};
  const unsigned short* Wp = Wb + (size_t)(m0 + srw) * 128 + kow;
  short8 a0 = *(const short8*)(Wp);
  short8 a1 = *(const short8*)(Wp + 8);
  for (int k0 = 0; k0 < 128; k0 += 32){
    __syncthreads();
    *(short8*)&Wls[srw * 40 + kow]     = a0;
    *(short8*)&Wls[srw * 40 + kow + 8] = a1;
    __syncthreads();
    if (k0 < 96){
      a0 = *(const short8*)(Wp + k0 + 32);
      a1 = *(const short8*)(Wp + k0 + 40);
    }
    short8 af[2], bfr[4];
    #pragma unroll
    for (int i = 0; i < 2; i++)
      af[i] = *(const short8*)&Xls[(w1 * 32 + i * 16 + lanelo) * 136 + k0 + quad * 8];
    #pragma unroll
    for (int j = 0; j < 4; j++)
      bfr[j] = *(const short8*)&Wls[(w2 * 64 + j * 16 + lanelo) * 40 + quad * 8];
    #pragma unroll
    for (int i = 0; i < 2; i++)
      #pragma unroll
      for (int j = 0; j < 4; j++)
        acc[i][j] = __builtin_amdgcn_mfma_f32_16x16x32_bf16(af[i], bfr[j], acc[i][j], 0, 0, 0);
  }
  __syncthreads();
  #pragma unroll
  for (int i = 0; i < 2; i++)
    #pragma unroll
    for (int j = 0; j < 4; j++){
      int pixloc = w1 * 32 + i * 16 + quad * 4;
      int mloc   = w2 * 64 + j * 16 + lanelo;
      #pragma unroll
      for (int r = 0; r < 4; r++)
        Xls[(pixloc + r) * 136 + mloc] = (short)f2b(acc[i][j][r]);
    }
  __syncthreads();
  unsigned short* Ob = Out + (size_t)b * cP * cC3;
  #pragma unroll
  for (int rr = 0; rr < 4; rr++){
    int id = t + rr * 256;
    int row = id >> 4, col8 = (id & 15) * 8;
    *(short8*)(Ob + (size_t)(p0 + row) * cC3 + m0 + col8) = *(const short8*)&Xls[row * 136 + col8];
  }
}

// ---- FUSED double GEMM, chunked-staging (128-wide K chunks, few barriers).
// MODE 1: Tr = acc;      LN(Base + acc) -> XB
// MODE 2: Tr = acc + R;  LN(Tr) -> XB
// GEMM2: Out2[p][m2] = XB[p][c] * W2[m2][c], K=128, M2 in 3 chunks of 128.
template<int MODE>
__global__ void __launch_bounds__(256) k_gfuse(const unsigned short* __restrict__ W1,
                                               const unsigned short* __restrict__ Xg,
                                               const float* __restrict__ R,
                                               const float* __restrict__ Base,
                                               const float* __restrict__ gamma,
                                               const float* __restrict__ beta,
                                               float* __restrict__ Tr,
                                               const unsigned short* __restrict__ W2,
                                               unsigned short* __restrict__ Out2,
                                               int K1, int PK1, int PITCH2, int M2LIM){
  __shared__ short WA[128 * 136];   // 128-row weight chunk, K<=128 staged whole
  __shared__ short XA[64 * 136];    // GEMM1 X chunk; aliased as OB in GEMM2
  __shared__ short XB[64 * 136];    // LN output
  __shared__ float gls[128], bls[128];
  __shared__ float psum[64], pssq[64];
  short* OB = XA;
  int b  = blockIdx.z;
  int p0 = blockIdx.x * 64;
  int t  = threadIdx.x;
  int lanelo = t & 15;
  int quad   = (t >> 4) & 3;
  int wv = t >> 6;
  int w2 = wv >> 1, w1 = wv & 1;
  int srow = t >> 1, shalf = t & 1;     // W staging: 128 rows x 2 col-halves
  int xrow = t >> 2, xq = t & 3;        // X staging: 64 rows x 4 col-quarters

  if (t < 128){ gls[t] = gamma[t]; bls[t] = beta[t]; }
  if (t < 64){ psum[t] = 0.f; pssq[t] = 0.f; }

  // ---------------- GEMM1: chunked K (2 barriers / 128-K chunk) ----------------
  float4v acc[4][2];
  #pragma unroll
  for (int i = 0; i < 4; i++){
    acc[i][0] = (float4v){0.f, 0.f, 0.f, 0.f};
    acc[i][1] = (float4v){0.f, 0.f, 0.f, 0.f};
  }
  const unsigned short* Xbase = Xg + (size_t)b * cP * PK1 + (size_t)(p0 + xrow) * PK1 + xq * 32;
  const unsigned short* Wbase = W1 + (size_t)srow * K1 + shalf * 64;
  for (int kb = 0; kb < K1; kb += 128){
    int CL = K1 - kb; if (CL > 128) CL = 128;
    __syncthreads();
    #pragma unroll
    for (int e = 0; e < 8; e++){
      int col = shalf * 64 + e * 8;
      if (col < CL)
        *(short8*)&WA[srow * 136 + col] = *(const short8*)(Wbase + kb + e * 8);
      // note: Wbase already offset by shalf*64; e*8 walks within the half
    }
    #pragma unroll
    for (int e = 0; e < 4; e++){
      int col = xq * 32 + e * 8;
      if (col < CL)
        *(short8*)&XA[xrow * 136 + col] = *(const short8*)(Xbase + kb + e * 8);
    }
    __syncthreads();
    for (int k0 = 0; k0 < CL; k0 += 32){
      short8 af[4], bfr[2];
      #pragma unroll
      for (int i = 0; i < 4; i++)
        af[i] = *(const short8*)&WA[(w2 * 64 + i * 16 + lanelo) * 136 + k0 + quad * 8];
      #pragma unroll
      for (int j = 0; j < 2; j++)
        bfr[j] = *(const short8*)&XA[(w1 * 32 + j * 16 + lanelo) * 136 + k0 + quad * 8];
      #pragma unroll
      for (int i = 0; i < 4; i++)
        #pragma unroll
        for (int j = 0; j < 2; j++)
          acc[i][j] = __builtin_amdgcn_mfma_f32_16x16x32_bf16(af[i], bfr[j], acc[i][j], 0, 0, 0);
    }
  }
  // ---------------- residual + Tr write + LN -> XB ----------------
  float lnv[4][2][4];
  #pragma unroll
  for (int i = 0; i < 4; i++)
    #pragma unroll
    for (int j = 0; j < 2; j++){
      int n = p0 + w1 * 32 + j * 16 + lanelo;
      #pragma unroll
      for (int r = 0; r < 4; r++){
        int m = w2 * 64 + i * 16 + quad * 4 + r;
        size_t idx = (size_t)b * cC * cP + (size_t)m * cP + n;
        float v = acc[i][j][r];
        if (MODE == 2) v += R[idx];
        Tr[idx] = v;
        if (MODE == 1) v += Base[idx];
        lnv[i][j][r] = v;
      }
    }
  __syncthreads();
  #pragma unroll
  for (int j = 0; j < 2; j++){
    int nl = w1 * 32 + j * 16 + lanelo;
    float s = 0.f, ss = 0.f;
    #pragma unroll
    for (int i = 0; i < 4; i++)
      #pragma unroll
      for (int r = 0; r < 4; r++){
        float v = lnv[i][j][r];
        s += v; ss += v * v;
      }
    atomicAdd(&psum[nl], s);
    atomicAdd(&pssq[nl], ss);
  }
  __syncthreads();
  #pragma unroll
  for (int j = 0; j < 2; j++){
    int nl = w1 * 32 + j * 16 + lanelo;
    float mean = psum[nl] * (1.f / cC);
    float var = pssq[nl] * (1.f / cC) - mean * mean;
    float rstd = rsqrtf(var + cEPS);
    #pragma unroll
    for (int i = 0; i < 4; i++)
      #pragma unroll
      for (int r = 0; r < 4; r++){
        int m = w2 * 64 + i * 16 + quad * 4 + r;
        XB[nl * 136 + m] = (short)f2b((lnv[i][j][r] - mean) * rstd * gls[m] + bls[m]);
      }
  }
  // ---------------- GEMM2: stage full 128-m W2 chunk, barrier-free K run ----------------
  unsigned short* Ob = Out2 + (size_t)b * cP * PITCH2;
  for (int mc = 0; mc < 3; mc++){
    __syncthreads();   // XB ready (mc=0) / prior OB store-reads + WA compute-reads done
    {
      const unsigned short* w2src = W2 + (size_t)(mc * 128 + srow) * 128 + shalf * 64;
      #pragma unroll
      for (int e = 0; e < 8; e++)
        *(short8*)&WA[srow * 136 + shalf * 64 + e * 8] = *(const short8*)(w2src + e * 8);
    }
    __syncthreads();
    float4v a2[2][4];
    #pragma unroll
    for (int i = 0; i < 2; i++)
      #pragma unroll
      for (int j = 0; j < 4; j++)
        a2[i][j] = (float4v){0.f, 0.f, 0.f, 0.f};
    #pragma unroll
    for (int k0 = 0; k0 < 128; k0 += 32){
      short8 af2[2], bf2[4];
      #pragma unroll
      for (int i = 0; i < 2; i++)
        af2[i] = *(const short8*)&XB[(w1 * 32 + i * 16 + lanelo) * 136 + k0 + quad * 8];
      #pragma unroll
      for (int j = 0; j < 4; j++)
        bf2[j] = *(const short8*)&WA[(w2 * 64 + j * 16 + lanelo) * 136 + k0 + quad * 8];
      #pragma unroll
      for (int i = 0; i < 2; i++)
        #pragma unroll
        for (int j = 0; j < 4; j++)
          a2[i][j] = __builtin_amdgcn_mfma_f32_16x16x32_bf16(af2[i], bf2[j], a2[i][j], 0, 0, 0);
    }
    #pragma unroll
    for (int i = 0; i < 2; i++)
      #pragma unroll
      for (int j = 0; j < 4; j++){
        int pixloc = w1 * 32 + i * 16 + quad * 4;
        int mloc   = w2 * 64 + j * 16 + lanelo;
        #pragma unroll
        for (int r = 0; r < 4; r++)
          OB[(pixloc + r) * 136 + mloc] = (short)f2b(a2[i][j][r]);
      }
    __syncthreads();
    #pragma unroll
    for (int rr = 0; rr < 4; rr++){
      int id = t + rr * 256;
      int row = id >> 4, col8 = (id & 15) * 8;
      int wcol = mc * 128 + col8;
      if (wcol < M2LIM)
        *(short8*)(Ob + (size_t)(p0 + row) * PITCH2 + wcol) = *(const short8*)&OB[row * 136 + col8];
    }
  }
}

// ---- final GEMM (ffc_out): chunked staging, Tr = acc + R (fp32 out, [c][p]) ----
__global__ void __launch_bounds__(256) k_g64d3(const unsigned short* __restrict__ Wb,
                                               const unsigned short* __restrict__ Xg,
                                               const float* __restrict__ R,
                                               float* __restrict__ Tr,
                                               int K, int PK){
  __shared__ short WA[128 * 136];
  __shared__ short XA[64 * 136];
  int b  = blockIdx.z;
  int p0 = blockIdx.x * 64;
  int t  = threadIdx.x;
  int lanelo = t & 15;
  int quad   = (t >> 4) & 3;
  int wv = t >> 6;
  int w2 = wv >> 1, w1 = wv & 1;
  int srow = t >> 1, shalf = t & 1;
  int xrow = t >> 2, xq = t & 3;

  float4v acc[4][2];
  #pragma unroll
  for (int i = 0; i < 4; i++){
    acc[i][0] = (float4v){0.f, 0.f, 0.f, 0.f};
    acc[i][1] = (float4v){0.f, 0.f, 0.f, 0.f};
  }
  const unsigned short* Xbase = Xg + (size_t)b * cP * PK + (size_t)(p0 + xrow) * PK + xq * 32;
  const unsigned short* Wbase = Wb + (size_t)srow * K + shalf * 64;
  for (int kb = 0; kb < K; kb += 128){
    int CL = K - kb; if (CL > 128) CL = 128;
    __syncthreads();
    #pragma unroll
    for (int e = 0; e < 8; e++){
      int col = shalf * 64 + e * 8;
      if (col < CL)
        *(short8*)&WA[srow * 136 + col] = *(const short8*)(Wbase + kb + e * 8);
    }
    #pragma unroll
    for (int e = 0; e < 4; e++){
      int col = xq * 32 + e * 8;
      if (col < CL)
        *(short8*)&XA[xrow * 136 + col] = *(const short8*)(Xbase + kb + e * 8);
    }
    __syncthreads();
    for (int k0 = 0; k0 < CL; k0 += 32){
      short8 af[4], bfr[2];
      #pragma unroll
      for (int i = 0; i < 4; i++)
        af[i] = *(const short8*)&WA[(w2 * 64 + i * 16 + lanelo) * 136 + k0 + quad * 8];
      #pragma unroll
      for (int j = 0; j < 2; j++)
        bfr[j] = *(const short8*)&XA[(w1 * 32 + j * 16 + lanelo) * 136 + k0 + quad * 8];
      #pragma unroll
      for (int i = 0; i < 4; i++)
        #pragma unroll
        for (int j = 0; j < 2; j++)
          acc[i][j] = __builtin_amdgcn_mfma_f32_16x16x32_bf16(af[i], bfr[j], acc[i][j], 0, 0, 0);
    }
  }
  #pragma unroll
  for (int i = 0; i < 4; i++)
    #pragma unroll
    for (int j = 0; j < 2; j++){
      int n = p0 + w1 * 32 + j * 16 + lanelo;
      #pragma unroll
      for (int r = 0; r < 4; r++){
        int m = w2 * 64 + i * 16 + quad * 4 + r;
        size_t idx = (size_t)b * cC * cP + (size_t)m * cP + n;
        Tr[idx] = acc[i][j][r] + R[idx];
      }
    }
}

// ---- depthwise 3x3 SAME, [p][c] layout, optional exact gelu ----
template<int GELU, int CCn, int PITCH>
__global__ void __launch_bounds__(256) k_dw(const unsigned short* __restrict__ in,
                                            const float* __restrict__ wt,
                                            unsigned short* __restrict__ out){
  __shared__ float wls[16 * 76];
  int t = threadIdx.x;
  int cbase = blockIdx.y * 128;
  for (int i = t; i < 16 * 72; i += 256){
    int cg = i / 72, rem = i - cg * 72;
    int tap = rem >> 3, j = rem & 7;
    int c = cbase + cg * 8 + j;
    wls[cg * 76 + rem] = (c < CCn) ? wt[c * 9 + tap] : 0.f;
  }
  __syncthreads();
  int cgl = t & 15, pixl = t >> 4;
  int c0 = cbase + cgl * 8;
  if (c0 >= PITCH) return;
  int p = blockIdx.x * 16 + pixl;
  int h = p >> 7, w = p & 127;
  int b = blockIdx.z;
  const unsigned short* ib = in + (size_t)b * cP * PITCH;
  float4 wreg[18];
  #pragma unroll
  for (int q = 0; q < 18; q++)
    wreg[q] = *(const float4*)&wls[cgl * 76 + q * 4];
  short8 v[9];
  #pragma unroll
  for (int ky = 0; ky < 3; ky++){
    int hh = h + ky - 1;
    bool okh = (unsigned)hh < (unsigned)cH;
    int hc = okh ? hh : h;
    #pragma unroll
    for (int kx = 0; kx < 3; kx++){
      int ww = w + kx - 1;
      bool okw = (unsigned)ww < (unsigned)cW;
      int wc = okw ? ww : w;
      short8 lv = *(const short8*)(ib + (size_t)(hc * cW + wc) * PITCH + c0);
      if (!(okh && okw)) lv = (short8){0,0,0,0,0,0,0,0};
      v[ky * 3 + kx] = lv;
    }
  }
  float acc[8] = {0,0,0,0,0,0,0,0};
  #pragma unroll
  for (int tap = 0; tap < 9; tap++){
    float4 w0 = wreg[tap * 2];
    float4 w1 = wreg[tap * 2 + 1];
    float wa[8] = {w0.x, w0.y, w0.z, w0.w, w1.x, w1.y, w1.z, w1.w};
    #pragma unroll
    for (int j = 0; j < 8; j++)
      acc[j] += wa[j] * bfu2f((unsigned short)v[tap][j]);
  }
  short8 ov;
  #pragma unroll
  for (int j = 0; j < 8; j++){
    float vv = acc[j];
    if (GELU) vv = 0.5f * vv * (1.f + erff(vv * 0.70710678118654752f));
    ov[j] = (short)f2b(vv);
  }
  *(short8*)(out + (size_t)b * cP * PITCH + (size_t)p * PITCH + c0) = ov;
}

// ---- fused depthwise-3x3 + RSA window attention ----
__global__ void __launch_bounds__(256) k_rsadw(const unsigned short* __restrict__ qkv,
                                               const float* __restrict__ wt,
                                               const float* __restrict__ temp,
                                               unsigned short* __restrict__ out){
  constexpr int QT = 0;
  constexpr int KT = 5120;
  constexpr int VO = 10240;
  constexpr int HA = 12416;
  constexpr int AT = 12416;
  __shared__ short lds[26528];
  __shared__ float nq[16], nk[16];
  int blk = blockIdx.x;
  int b  = blk >> 10;
  int nw = blk & 1023;
  int hb = nw >> 5, wb = nw & 31;
  int t = threadIdx.x;
  #pragma unroll
  for (int j = 0; j < 5; j++)
    *(short8*)&lds[t * 40 + j * 8] = (short8){0,0,0,0,0,0,0,0};
  if (t < 16) nq[t] = 0.f;
  else if (t < 32) nk[t - 16] = 0.f;
  __syncthreads();
  const unsigned short* base = qkv + (size_t)b * cP * cC3;
  #pragma unroll
  for (int r = 0; r < 7; r++){
    int i = t + 256 * r;
    if (i < 1728){
      int pix6 = i / 48;
      int cg = i - pix6 * 48;
      int hy = pix6 / 6, wx = pix6 - hy * 6;
      int hh = hb * 4 + hy - 1;
      int ww = wb * 4 + wx - 1;
      short8 v = (short8){0,0,0,0,0,0,0,0};
      if ((unsigned)hh < (unsigned)cH && (unsigned)ww < (unsigned)cW)
        v = *(const short8*)(base + (size_t)(hh * cW + ww) * cC3 + cg * 8);
      *(short8*)&lds[HA + pix6 * 392 + cg * 8] = v;
    }
  }
  __syncthreads();
  {
    int px = t & 15, grp = t >> 4;
    int py = px >> 2, pw = px & 3;
    #pragma unroll
    for (int g = 0; g < 3; g++){
      int c0 = grp * 24 + g * 8;
      const float4* wq = (const float4*)(wt + (size_t)c0 * 9);
      float wa[72];
      #pragma unroll
      for (int q = 0; q < 18; q++){
        float4 v4 = wq[q];
        wa[q * 4 + 0] = v4.x; wa[q * 4 + 1] = v4.y;
        wa[q * 4 + 2] = v4.z; wa[q * 4 + 3] = v4.w;
      }
      float acc8[8] = {0,0,0,0,0,0,0,0};
      #pragma unroll
      for (int ky = 0; ky < 3; ky++)
        #pragma unroll
        for (int kx = 0; kx < 3; kx++){
          short8 iv = *(const short8*)&lds[HA + ((py + ky) * 6 + pw + kx) * 392 + c0];
          int tap = ky * 3 + kx;
          #pragma unroll
          for (int e = 0; e < 8; e++)
            acc8[e] += wa[e * 9 + tap] * bfu2f((unsigned short)iv[e]);
        }
      if (c0 < 256){
        int isQ = c0 < 128;
        int off = isQ ? (QT + c0 * 40) : (KT + (c0 - 128) * 40);
        float s = 0.f;
        #pragma unroll
        for (int e = 0; e < 8; e++){
          unsigned short us = f2b(acc8[e]);
          float f = bfu2f(us);
          s += f * f;
          lds[off + e * 40 + px] = (short)us;
        }
        atomicAdd(isQ ? &nq[px] : &nk[px], s);
      } else {
        short8 sv;
        #pragma unroll
        for (int e = 0; e < 8; e++) sv[e] = (short)f2b(acc8[e]);
        *(short8*)&lds[VO + px * 136 + (c0 - 256)] = sv;
      }
    }
  }
  __syncthreads();
  float T = temp[0];
  #pragma unroll
  for (int r = 0; r < 8; r++){
    int idx = t + 256 * r;
    int c = idx >> 4, p = idx & 15;
    float sc = (1.f / fmaxf(sqrtf(nq[p]), 1e-12f)) * (1.f / fmaxf(sqrtf(nk[p]), 1e-12f));
    int a = QT + c * 40 + p;
    lds[a] = (short)f2b(bfu2f((unsigned short)lds[a]) * sc);
  }
  __syncthreads();
  int lanelo = t & 15;
  int quad = (t >> 4) & 3;
  int wv = t >> 6;
  float4v oacc[2];
  oacc[0] = (float4v){0.f,0.f,0.f,0.f};
  oacc[1] = (float4v){0.f,0.f,0.f,0.f};
  for (int ch = 0; ch < 2; ch++){
    #pragma unroll
    for (int ct = 0; ct < 4; ct++){
      int c0 = ch * 64 + ct * 16;
      short8 af = *(const short8*)&lds[QT + (c0 + lanelo) * 40 + quad * 8];
      #pragma unroll
      for (int dt = 0; dt < 2; dt++){
        int d0 = wv * 32 + dt * 16;
        short8 bf = *(const short8*)&lds[KT + (d0 + lanelo) * 40 + quad * 8];
        float4v acc = __builtin_amdgcn_mfma_f32_16x16x32_bf16(af, bf,
                        (float4v){0.f,0.f,0.f,0.f}, 0, 0, 0);
        short4v sv;
        #pragma unroll
        for (int r2 = 0; r2 < 4; r2++) sv[r2] = (short)f2b(fmaxf(acc[r2] * T, 0.f));
        *(short4v*)&lds[AT + (d0 + lanelo) * 72 + ct * 16 + quad * 4] = sv;
      }
    }
    __syncthreads();
    #pragma unroll
    for (int dt = 0; dt < 2; dt++){
      int d0 = wv * 32 + dt * 16;
      #pragma unroll
      for (int kk = 0; kk < 2; kk++){
        short8 av8 = *(const short8*)&lds[VO + lanelo * 136 + ch * 64 + kk * 32 + quad * 8];
        short8 bv8 = *(const short8*)&lds[AT + (d0 + lanelo) * 72 + kk * 32 + quad * 8];
        oacc[dt] = __builtin_amdgcn_mfma_f32_16x16x32_bf16(av8, bv8, oacc[dt], 0, 0, 0);
      }
    }
    __syncthreads();
  }
  #pragma unroll
  for (int dt = 0; dt < 2; dt++){
    int d = wv * 32 + dt * 16 + lanelo;
    #pragma unroll
    for (int r2 = 0; r2 < 4; r2++){
      int p = quad * 4 + r2;
      lds[p * 136 + d] = (short)f2b(oacc[dt][r2]);
    }
  }
  __syncthreads();
  {
    int px = t >> 4, cg = (t & 15) * 8;
    int h2 = (hb * 4 + (px >> 2) + 2) & (cH - 1);
    int w2 = (wb * 4 + (px & 3) + 2) & (cW - 1);
    short8 sv = *(const short8*)&lds[px * 136 + cg];
    *(short8*)(out + (size_t)b * cP * cC + (size_t)(h2 * cW + w2) * cC + cg) = sv;
  }
}

// ---- GSA Gram with on-the-fly depthwise-3x3 (Q,K channels of this head) ----
__global__ void __launch_bounds__(256) k_gramdw(const unsigned short* __restrict__ Ain,
                                                const float* __restrict__ dww,
                                                float* __restrict__ S,
                                                float* __restrict__ Qn,
                                                float* __restrict__ Kn){
  __shared__ float qs[32][132];
  __shared__ float ks[32][132];
  __shared__ float wdw[576];
  int blk = blockIdx.x;
  int chunk = blk & 127;
  int bh = blk >> 7;
  int b = bh >> 2, hd = bh & 3;
  int t = threadIdx.x;
  for (int i = t; i < 576; i += 256){
    int lc = i / 9, tpq = i - lc * 9;
    int c = (lc < 32) ? (hd * 32 + lc) : (128 + hd * 32 + (lc - 32));
    wdw[i] = dww[c * 9 + tpq];
  }
  __syncthreads();
  int row = t >> 1;
  int half = t & 1;
  int h = chunk, w = row;
  const unsigned short* Ab = Ain + (size_t)b * cP * cC3;
  float qa[16], ka[16];
  #pragma unroll
  for (int e = 0; e < 16; e++){ qa[e] = 0.f; ka[e] = 0.f; }
  #pragma unroll
  for (int ky = 0; ky < 3; ky++){
    int hh = h + ky - 1;
    if ((unsigned)hh >= (unsigned)cH) continue;
    #pragma unroll
    for (int kx = 0; kx < 3; kx++){
      int ww = w + kx - 1;
      if ((unsigned)ww >= (unsigned)cW) continue;
      const unsigned short* pp = Ab + (size_t)(hh * cW + ww) * cC3 + hd * 32 + half * 16;
      short8 q0 = *(const short8*)pp;
      short8 q1 = *(const short8*)(pp + 8);
      short8 k0v = *(const short8*)(pp + 128);
      short8 k1v = *(const short8*)(pp + 136);
      int tpi = ky * 3 + kx;
      #pragma unroll
      for (int e = 0; e < 8; e++){
        qa[e]     += wdw[(half * 16 + e) * 9 + tpi]          * bfu2f((unsigned short)q0[e]);
        qa[8 + e] += wdw[(half * 16 + 8 + e) * 9 + tpi]      * bfu2f((unsigned short)q1[e]);
        ka[e]     += wdw[(32 + half * 16 + e) * 9 + tpi]     * bfu2f((unsigned short)k0v[e]);
        ka[8 + e] += wdw[(32 + half * 16 + 8 + e) * 9 + tpi] * bfu2f((unsigned short)k1v[e]);
      }
    }
  }
  #pragma unroll
  for (int e = 0; e < 16; e++){
    qs[half * 16 + e][row] = bfu2f(f2b(qa[e]));
    ks[half * 16 + e][row] = bfu2f(f2b(ka[e]));
  }
  __syncthreads();
  if (t < 64){
    const float* rowp = (t < 32) ? qs[t] : ks[t - 32];
    float s = 0.f;
    #pragma unroll
    for (int i = 0; i < 128; i += 4){
      float4 v = *(const float4*)(rowp + i);
      s += v.x*v.x + v.y*v.y + v.z*v.z + v.w*v.w;
    }
    if (t < 32) atomicAdd(&Qn[bh * 32 + t], s);
    else        atomicAdd(&Kn[bh * 32 + (t - 32)], s);
  }
  int cc = (t >> 4) * 2;
  int dd = t & 15;
  float a00 = 0.f, a01 = 0.f, a10 = 0.f, a11 = 0.f;
  for (int n = 0; n < 128; n += 4){
    float4 q0 = *(const float4*)&qs[cc][n];
    float4 q1 = *(const float4*)&qs[cc + 1][n];
    float4 k0 = *(const float4*)&ks[dd][n];
    float4 k1 = *(const float4*)&ks[dd + 16][n];
    a00 += q0.x*k0.x + q0.y*k0.y + q0.z*k0.z + q0.w*k0.w;
    a01 += q0.x*k1.x + q0.y*k1.y + q0.z*k1.z + q0.w*k1.w;
    a10 += q1.x*k0.x + q1.y*k0.y + q1.z*k0.z + q1.w*k0.w;
    a11 += q1.x*k1.x + q1.y*k1.y + q1.z*k1.z + q1.w*k1.w;
  }
  float* Sb = S + (size_t)bh * 1024;
  atomicAdd(&Sb[cc * 32 + dd], a00);
  atomicAdd(&Sb[cc * 32 + dd + 16], a01);
  atomicAdd(&Sb[(cc + 1) * 32 + dd], a10);
  atomicAdd(&Sb[(cc + 1) * 32 + dd + 16], a11);
}

// ---- GSA apply via MFMA with on-the-fly depthwise-3x3 for V ----
__global__ void __launch_bounds__(256) k_applydw(const unsigned short* __restrict__ Ain,
                                                 const float* __restrict__ dww,
                                                 const float* __restrict__ S,
                                                 const float* __restrict__ Qn,
                                                 const float* __restrict__ Kn,
                                                 const float* __restrict__ temp,
                                                 unsigned short* __restrict__ out){
  __shared__ short atb[128 * 40];
  __shared__ short OT[64 * 136];
  __shared__ float wdw[1152];
  int b = blockIdx.y;
  int nbase = blockIdx.x * 64;
  int t = threadIdx.x;
  float T = temp[0];
  for (int i = t; i < 1152; i += 256)
    wdw[i] = dww[2304 + i];
  #pragma unroll
  for (int it = 0; it < 16; it++){
    int i = t + it * 256;
    int c = i >> 5, d = i & 31;
    int hd = c >> 5, cl = c & 31;
    int bh = b * 4 + hd;
    float nqv = fmaxf(sqrtf(Qn[bh * 32 + cl]), 1e-12f);
    float nkv = fmaxf(sqrtf(Kn[bh * 32 + d]), 1e-12f);
    float v = fmaxf(S[(size_t)bh * 1024 + cl * 32 + d] / (nqv * nkv) * T, 0.f);
    atb[c * 40 + d] = (short)f2b(v);
  }
  __syncthreads();
  int lanelo = t & 15, quad = (t >> 4) & 3, wv = t >> 6;
  int pix = nbase + wv * 16 + lanelo;
  int h = pix >> 7, w = pix & 127;
  const unsigned short* Ab = Ain + (size_t)b * cP * cC3;
  #pragma unroll
  for (int hd = 0; hd < 4; hd++){
    float va[8] = {0,0,0,0,0,0,0,0};
    #pragma unroll
    for (int ky = 0; ky < 3; ky++){
      int hh = h + ky - 1;
      if ((unsigned)hh >= (unsigned)cH) continue;
      #pragma unroll
      for (int kx = 0; kx < 3; kx++){
        int ww = w + kx - 1;
        if ((unsigned)ww >= (unsigned)cW) continue;
        short8 iv = *(const short8*)(Ab + (size_t)(hh * cW + ww) * cC3 + 256 + hd * 32 + quad * 8);
        int tpi = ky * 3 + kx;
        #pragma unroll
        for (int e = 0; e < 8; e++)
          va[e] += wdw[(hd * 32 + quad * 8 + e) * 9 + tpi] * bfu2f((unsigned short)iv[e]);
      }
    }
    short8 af;
    #pragma unroll
    for (int e = 0; e < 8; e++) af[e] = (short)f2b(va[e]);
    #pragma unroll
    for (int cth = 0; cth < 2; cth++){
      int c0 = hd * 32 + cth * 16;
      short8 bf = *(const short8*)&atb[(c0 + lanelo) * 40 + quad * 8];
      float4v acc = __builtin_amdgcn_mfma_f32_16x16x32_bf16(af, bf,
                      (float4v){0.f,0.f,0.f,0.f}, 0, 0, 0);
      #pragma unroll
      for (int r = 0; r < 4; r++)
        OT[(wv * 16 + quad * 4 + r) * 136 + c0 + lanelo] = (short)f2b(acc[r]);
    }
  }
  __syncthreads();
  unsigned short* ob = out + (size_t)b * cP * cC;
  #pragma unroll
  for (int rr = 0; rr < 4; rr++){
    int id = t + rr * 256;
    int row = id >> 4, col8 = (id & 15) * 8;
    *(short8*)(ob + (size_t)(nbase + row) * cC + col8) = *(const short8*)&OT[row * 136 + col8];
  }
}

extern "C" void kernel_launch(void* const* d_in, const int* in_sizes, int n_in,
                              void* d_out, int out_size, void* d_ws, size_t ws_size,
                              hipStream_t stream){
  const float* x     = (const float*)d_in[0];
  const float* w_s0  = (const float*)d_in[1];
  const float* b_s0  = (const float*)d_in[2];
  const float* w_s2  = (const float*)d_in[3];
  const float* b_s2  = (const float*)d_in[4];
  const float* rsa_qkv  = (const float*)d_in[5];
  const float* rsa_dw   = (const float*)d_in[6];
  const float* rsa_proj = (const float*)d_in[7];
  const float* rsa_temp = (const float*)d_in[8];
  const float* ffs_in   = (const float*)d_in[9];
  const float* ffs_dw   = (const float*)d_in[10];
  const float* ffs_out  = (const float*)d_in[11];
  const float* w_c0  = (const float*)d_in[12];
  const float* b_c0  = (const float*)d_in[13];
  const float* w_c2  = (const float*)d_in[14];
  const float* b_c2  = (const float*)d_in[15];
  const float* gsa_qkv  = (const float*)d_in[16];
  const float* gsa_dw   = (const float*)d_in[17];
  const float* gsa_proj = (const float*)d_in[18];
  const float* gsa_temp = (const float*)d_in[19];
  const float* ffc_in   = (const float*)d_in[20];
  const float* ffc_dw   = (const float*)d_in[21];
  const float* ffc_out  = (const float*)d_in[22];

  const size_t szC  = (size_t)cB * cC * cP;
  const size_t szC3 = (size_t)cB * cC3 * cP;
  float* XF = (float*)d_ws;
  float* XS = XF + szC;
  unsigned short* LO   = (unsigned short*)(XS + szC);
  unsigned short* Abuf = LO + szC;
  unsigned short* Bbuf = Abuf + szC3;
  float* S  = (float*)(Bbuf + szC3);
  float* Qn = S + 8192;
  float* Kn = Qn + 256;
  float* AT = Kn + 256;
  unsigned short* WB = (unsigned short*)(AT + 1024);
  unsigned short* W_QKV_S = WB;
  unsigned short* W_QKV_C = WB + 49152;
  unsigned short* W_FIN_S = WB + 98304;
  unsigned short* W_FIN_C = WB + 147456;
  unsigned short* W_PRJ_S = WB + 196608;
  unsigned short* W_PRJ_C = WB + 212992;
  unsigned short* W_FO_S  = WB + 229376;
  unsigned short* W_FO_C  = WB + 274432;

  dim3 t256(256);
  dim3 gG1(cP / 64 * 3 * cB);
  dim3 gG64(cP / 64, 1, cB);
  dim3 gDW(cP / 16, 3, cB);

  k_wcvt<<<dim3(1282), t256, 0, stream>>>(rsa_qkv, gsa_qkv, ffs_in, ffc_in,
                                          rsa_proj, gsa_proj, ffs_out, ffc_out, WB, S);

  // ---------------- spatial (RSA) block ----------------
  k_gemmLN<<<gG1, t256, 0, stream>>>(W_QKV_S, x, w_s0, b_s0, Abuf);
  k_rsadw<<<dim3(cB * cNW), t256, 0, stream>>>(Abuf, rsa_dw, rsa_temp, LO);
  // PRJ_S + LN(w_s2) + FIN_S fused (chunked staging)
  k_gfuse<1><<<gG64, t256, 0, stream>>>(W_PRJ_S, LO, nullptr, x, w_s2, b_s2, XS,
                                        W_FIN_S, Abuf, 128, 128, 352, 352);
  k_dw<1,340,352><<<gDW, t256, 0, stream>>>(Abuf, ffs_dw, Bbuf);
  // FO_S + residual(XS) + LN(w_c0) + QKV_C fused
  k_gfuse<2><<<gG64, t256, 0, stream>>>(W_FO_S, Bbuf, XS, nullptr, w_c0, b_c0, XF,
                                        W_QKV_C, Abuf, 352, 352, 384, 384);

  // ---------------- channel (GSA) block ----------------
  k_gramdw<<<dim3(1024), t256, 0, stream>>>(Abuf, gsa_dw, S, Qn, Kn);
  k_applydw<<<dim3(cP / 64, cB), t256, 0, stream>>>(Abuf, gsa_dw, S, Qn, Kn, gsa_temp, LO);
  // PRJ_C + LN(w_c2) + FIN_C fused
  k_gfuse<1><<<gG64, t256, 0, stream>>>(W_PRJ_C, LO, nullptr, XF, w_c2, b_c2, XS,
                                        W_FIN_C, Abuf, 128, 128, 352, 352);
  k_dw<1,340,352><<<gDW, t256, 0, stream>>>(Abuf, ffc_dw, Bbuf);
  k_g64d3<<<gG64, t256, 0, stream>>>(W_FO_C, Bbuf, XS, (float*)d_out, 352, 352);
}

// Round 10
// 321.483 us; speedup vs baseline: 1.0601x; 1.0601x over previous
//
#include <hip/hip_runtime.h>
#include <hip/hip_bf16.h>
#include <math.h>

typedef __hip_bfloat16 bf16;
typedef __attribute__((ext_vector_type(8))) short short8;
typedef __attribute__((ext_vector_type(4))) short short4v;
typedef __attribute__((ext_vector_type(4))) float float4v;

static constexpr int cB  = 2;
static constexpr int cC  = 128;
static constexpr int cH  = 128;
static constexpr int cW  = 128;
static constexpr int cP  = cH * cW;       // 16384
static constexpr int cC3 = 384;
static constexpr int cHID = 340;
static constexpr int cNW = 1024;
static constexpr float cEPS = 1e-6f;

__device__ __forceinline__ float bfu2f(unsigned short u){
  union { unsigned int i; float f; } c; c.i = ((unsigned int)u) << 16; return c.f;
}
__device__ __forceinline__ unsigned short f2b(float f){
  union { float f; unsigned int u; } c; c.f = f;
  unsigned int r = c.u + 0x7FFFu + ((c.u >> 16) & 1u);
  return (unsigned short)(r >> 16);
}

// ---- convert all 8 weight matrices fp32 -> bf16 (with padding) into WB; tail zeroes S
__global__ void k_wcvt(const float* __restrict__ qkv_s, const float* __restrict__ qkv_c,
                       const float* __restrict__ fin_s, const float* __restrict__ fin_c,
                       const float* __restrict__ prj_s, const float* __restrict__ prj_c,
                       const float* __restrict__ fo_s,  const float* __restrict__ fo_c,
                       unsigned short* __restrict__ WB, float* __restrict__ S){
  int i = blockIdx.x * 256 + threadIdx.x;
  if (i >= 319488){
    int j = i - 319488;
    if (j < 8704) S[j] = 0.f;
    return;
  }
  float v;
  if (i < 98304){
    v = (i < 49152) ? qkv_s[i] : qkv_c[i - 49152];
  } else if (i < 196608){
    int j = (i < 147456) ? (i - 98304) : (i - 147456);
    int row = j >> 7, col = j & 127;
    const float* src = (i < 147456) ? fin_s : fin_c;
    v = (row < cHID) ? src[row * 128 + col] : 0.f;
  } else if (i < 229376){
    v = (i < 212992) ? prj_s[i - 196608] : prj_c[i - 212992];
  } else {
    int j = (i < 274432) ? (i - 229376) : (i - 274432);
    int row = j / 352, col = j - row * 352;
    const float* src = (i < 274432) ? fo_s : fo_c;
    v = (col < cHID) ? src[row * cHID + col] : 0.f;
  }
  WB[i] = f2b(v);
}

// ---- fused LN + roll + QKV GEMM (spatial branch entry) ----
__global__ void __launch_bounds__(256) k_gemmLN(const unsigned short* __restrict__ Wb,
                                                const float* __restrict__ Xf,
                                                const float* __restrict__ gamma,
                                                const float* __restrict__ beta,
                                                unsigned short* __restrict__ Out){
  __shared__ short Xls[64 * 136];
  __shared__ short Wls[128 * 40];
  __shared__ float gls[128], bls[128];
  __shared__ float psum[64], pssq[64];
  int bid = blockIdx.x;
  int s  = (bid & 7) * 192 + (bid >> 3);
  int mt = s % 3;
  int r3 = s / 3;
  int pt = r3 & 255;
  int b  = r3 >> 8;
  int p0 = pt * 64;
  int m0 = mt * 128;
  int t  = threadIdx.x;
  int px = t & 63, cq = t >> 6;
  if (t < 64){ psum[t] = 0.f; pssq[t] = 0.f; }
  if (t < 128){ gls[t] = gamma[t]; bls[t] = beta[t]; }
  int rh = p0 >> 7, w0 = p0 & 127;
  int hs = (rh + 2) & (cH - 1);
  int sp = hs * cW + ((w0 + 2 + px) & (cW - 1));
  const float* xb = Xf + (size_t)b * cC * cP + sp;
  float xr[32];
  float s1 = 0.f, s2 = 0.f;
  #pragma unroll
  for (int j = 0; j < 32; j++){
    float v = xb[(size_t)(cq * 32 + j) * cP];
    xr[j] = v; s1 += v; s2 += v * v;
  }
  __syncthreads();
  atomicAdd(&psum[px], s1);
  atomicAdd(&pssq[px], s2);
  __syncthreads();
  float mean = psum[px] * (1.f / cC);
  float var  = pssq[px] * (1.f / cC) - mean * mean;
  float rstd = rsqrtf(var + cEPS);
  #pragma unroll
  for (int k = 0; k < 4; k++){
    short8 tv;
    #pragma unroll
    for (int e = 0; e < 8; e++){
      int c = cq * 32 + k * 8 + e;
      tv[e] = (short)f2b((xr[k * 8 + e] - mean) * rstd * gls[c] + bls[c]);
    }
    *(short8*)&Xls[px * 136 + cq * 32 + k * 8] = tv;
  }
  int lanelo = t & 15;
  int quad   = (t >> 4) & 3;
  int wv = t >> 6;
  int w1 = wv & 1;
  int w2 = wv >> 1;
  int srw = t >> 1;
  int kow = (t & 1) * 16;
  float4v acc[2][4];
  #pragma unroll
  for (int i = 0; i < 2; i++)
    #pragma unroll
    for (int j = 0; j < 4; j++)
      acc[i][j] = (float4v){0.f, 0.f, 0.f, 0.f};
  const unsigned short* Wp = Wb + (size_t)(m0 + srw) * 128 + kow;
  short8 a0 = *(const short8*)(Wp);
  short8 a1 = *(const short8*)(Wp + 8);
  for (int k0 = 0; k0 < 128; k0 += 32){
    __syncthreads();
    *(short8*)&Wls[srw * 40 + kow]     = a0;
    *(short8*)&Wls[srw * 40 + kow + 8] = a1;
    __syncthreads();
    if (k0 < 96){
      a0 = *(const short8*)(Wp + k0 + 32);
      a1 = *(const short8*)(Wp + k0 + 40);
    }
    short8 af[2], bfr[4];
    #pragma unroll
    for (int i = 0; i < 2; i++)
      af[i] = *(const short8*)&Xls[(w1 * 32 + i * 16 + lanelo) * 136 + k0 + quad * 8];
    #pragma unroll
    for (int j = 0; j < 4; j++)
      bfr[j] = *(const short8*)&Wls[(w2 * 64 + j * 16 + lanelo) * 40 + quad * 8];
    #pragma unroll
    for (int i = 0; i < 2; i++)
      #pragma unroll
      for (int j = 0; j < 4; j++)
        acc[i][j] = __builtin_amdgcn_mfma_f32_16x16x32_bf16(af[i], bfr[j], acc[i][j], 0, 0, 0);
  }
  __syncthreads();
  #pragma unroll
  for (int i = 0; i < 2; i++)
    #pragma unroll
    for (int j = 0; j < 4; j++){
      int pixloc = w1 * 32 + i * 16 + quad * 4;
      int mloc   = w2 * 64 + j * 16 + lanelo;
      #pragma unroll
      for (int r = 0; r < 4; r++)
        Xls[(pixloc + r) * 136 + mloc] = (short)f2b(acc[i][j][r]);
    }
  __syncthreads();
  unsigned short* Ob = Out + (size_t)b * cP * cC3;
  #pragma unroll
  for (int rr = 0; rr < 4; rr++){
    int id = t + rr * 256;
    int row = id >> 4, col8 = (id & 15) * 8;
    *(short8*)(Ob + (size_t)(p0 + row) * cC3 + m0 + col8) = *(const short8*)&Xls[row * 136 + col8];
  }
}

// ---- FUSED double GEMM: GEMM1 (+res) + LN (LDS-resident) + GEMM2 over same 64px tile.
// MODE 1: Tr = acc;      LN(Base + acc) -> XB   (proj+LN, then FIN GEMM)
// MODE 2: Tr = acc + R;  LN(Tr) -> XB           (ffn_out+LN, then QKV GEMM)
// GEMM2: Out2[p][m2] = XB[p][c] * W2[m2][c], K=128, M2 in 3 chunks of 128.
template<int MODE>
__global__ void __launch_bounds__(256) k_gfuse(const unsigned short* __restrict__ W1,
                                               const unsigned short* __restrict__ Xg,
                                               const float* __restrict__ R,
                                               const float* __restrict__ Base,
                                               const float* __restrict__ gamma,
                                               const float* __restrict__ beta,
                                               float* __restrict__ Tr,
                                               const unsigned short* __restrict__ W2,
                                               unsigned short* __restrict__ Out2,
                                               int K1, int PK1, int PITCH2, int M2LIM){
  __shared__ short SM[25088];           // XA(2560) | WA(5120) | XB(8704) | OB(8704)
  __shared__ float gls[128], bls[128];
  __shared__ float psum[64], pssq[64];
  short* XA = SM;
  short* WA = SM + 2560;
  short* XB = SM + 7680;
  short* OB = SM + 16384;
  int b  = blockIdx.z;
  int p0 = blockIdx.x * 64;
  int t  = threadIdx.x;
  int lanelo = t & 15;
  int quad   = (t >> 4) & 3;
  int wv = t >> 6;
  int w2 = wv >> 1, w1 = wv & 1;
  int srw = t >> 1;
  int kow = (t & 1) * 16;
  int srx = t >> 2;
  int kox = (t & 3) * 8;

  if (t < 128){ gls[t] = gamma[t]; bls[t] = beta[t]; }
  if (t < 64){ psum[t] = 0.f; pssq[t] = 0.f; }

  // ---------------- GEMM1 (pipelined, identical structure to k_gemm64) ----------------
  float4v acc[4][2];
  #pragma unroll
  for (int i = 0; i < 4; i++){
    acc[i][0] = (float4v){0.f, 0.f, 0.f, 0.f};
    acc[i][1] = (float4v){0.f, 0.f, 0.f, 0.f};
  }
  const unsigned short* Xp = Xg + (size_t)b * cP * PK1 + (size_t)(p0 + srx) * PK1 + kox;
  const unsigned short* Wp = W1 + (size_t)srw * K1 + kow;
  short8 xv  = *(const short8*)(Xp);
  short8 wv0 = *(const short8*)(Wp);
  short8 wv1 = *(const short8*)(Wp + 8);
  for (int k0 = 0; k0 < K1; k0 += 32){
    __syncthreads();
    *(short8*)&WA[srw * 40 + kow]     = wv0;
    *(short8*)&WA[srw * 40 + kow + 8] = wv1;
    *(short8*)&XA[srx * 40 + kox]     = xv;
    __syncthreads();
    if (k0 + 32 < K1){
      xv  = *(const short8*)(Xp + k0 + 32);
      wv0 = *(const short8*)(Wp + k0 + 32);
      wv1 = *(const short8*)(Wp + k0 + 40);
    }
    short8 af[4], bfr[2];
    #pragma unroll
    for (int i = 0; i < 4; i++)
      af[i] = *(const short8*)&WA[(w2 * 64 + i * 16 + lanelo) * 40 + quad * 8];
    #pragma unroll
    for (int j = 0; j < 2; j++)
      bfr[j] = *(const short8*)&XA[(w1 * 32 + j * 16 + lanelo) * 40 + quad * 8];
    #pragma unroll
    for (int i = 0; i < 4; i++)
      #pragma unroll
      for (int j = 0; j < 2; j++)
        acc[i][j] = __builtin_amdgcn_mfma_f32_16x16x32_bf16(af[i], bfr[j], acc[i][j], 0, 0, 0);
  }
  // ---------------- residual + Tr write + LN -> XB ----------------
  float lnv[4][2][4];
  #pragma unroll
  for (int i = 0; i < 4; i++)
    #pragma unroll
    for (int j = 0; j < 2; j++){
      int n = p0 + w1 * 32 + j * 16 + lanelo;
      #pragma unroll
      for (int r = 0; r < 4; r++){
        int m = w2 * 64 + i * 16 + quad * 4 + r;
        size_t idx = (size_t)b * cC * cP + (size_t)m * cP + n;
        float v = acc[i][j][r];
        if (MODE == 2) v += R[idx];
        Tr[idx] = v;
        if (MODE == 1) v += Base[idx];
        lnv[i][j][r] = v;
      }
    }
  __syncthreads();
  #pragma unroll
  for (int j = 0; j < 2; j++){
    int nl = w1 * 32 + j * 16 + lanelo;
    float s = 0.f, ss = 0.f;
    #pragma unroll
    for (int i = 0; i < 4; i++)
      #pragma unroll
      for (int r = 0; r < 4; r++){
        float v = lnv[i][j][r];
        s += v; ss += v * v;
      }
    atomicAdd(&psum[nl], s);
    atomicAdd(&pssq[nl], ss);
  }
  __syncthreads();
  #pragma unroll
  for (int j = 0; j < 2; j++){
    int nl = w1 * 32 + j * 16 + lanelo;
    float mean = psum[nl] * (1.f / cC);
    float var = pssq[nl] * (1.f / cC) - mean * mean;
    float rstd = rsqrtf(var + cEPS);
    #pragma unroll
    for (int i = 0; i < 4; i++)
      #pragma unroll
      for (int r = 0; r < 4; r++){
        int m = w2 * 64 + i * 16 + quad * 4 + r;
        XB[nl * 136 + m] = (short)f2b((lnv[i][j][r] - mean) * rstd * gls[m] + bls[m]);
      }
  }
  // ---------------- GEMM2: X = XB (LDS), W2 streamed, 3 chunks of 128 m ----------------
  const unsigned short* Wq = W2 + (size_t)srw * 128 + kow;
  short8 b0 = *(const short8*)(Wq);
  short8 b1 = *(const short8*)(Wq + 8);
  unsigned short* Ob = Out2 + (size_t)b * cP * PITCH2;
  for (int mc = 0; mc < 3; mc++){
    float4v a2[2][4];
    #pragma unroll
    for (int i = 0; i < 2; i++)
      #pragma unroll
      for (int j = 0; j < 4; j++)
        a2[i][j] = (float4v){0.f, 0.f, 0.f, 0.f};
    for (int k0 = 0; k0 < 128; k0 += 32){
      __syncthreads();
      *(short8*)&WA[srw * 40 + kow]     = b0;
      *(short8*)&WA[srw * 40 + kow + 8] = b1;
      __syncthreads();
      int nk = mc * 128 + k0 + 32;
      if (nk < 384){
        const unsigned short* np = W2 + (size_t)((nk >> 7) * 128 + srw) * 128 + (nk & 127) + kow;
        b0 = *(const short8*)(np);
        b1 = *(const short8*)(np + 8);
      }
      short8 af2[2], bf2[4];
      #pragma unroll
      for (int i = 0; i < 2; i++)
        af2[i] = *(const short8*)&XB[(w1 * 32 + i * 16 + lanelo) * 136 + k0 + quad * 8];
      #pragma unroll
      for (int j = 0; j < 4; j++)
        bf2[j] = *(const short8*)&WA[(w2 * 64 + j * 16 + lanelo) * 40 + quad * 8];
      #pragma unroll
      for (int i = 0; i < 2; i++)
        #pragma unroll
        for (int j = 0; j < 4; j++)
          a2[i][j] = __builtin_amdgcn_mfma_f32_16x16x32_bf16(af2[i], bf2[j], a2[i][j], 0, 0, 0);
    }
    // stage chunk to OB, then coalesced stores
    #pragma unroll
    for (int i = 0; i < 2; i++)
      #pragma unroll
      for (int j = 0; j < 4; j++){
        int pixloc = w1 * 32 + i * 16 + quad * 4;
        int mloc   = w2 * 64 + j * 16 + lanelo;
        #pragma unroll
        for (int r = 0; r < 4; r++)
          OB[(pixloc + r) * 136 + mloc] = (short)f2b(a2[i][j][r]);
      }
    __syncthreads();
    #pragma unroll
    for (int rr = 0; rr < 4; rr++){
      int id = t + rr * 256;
      int row = id >> 4, col8 = (id & 15) * 8;
      int wcol = mc * 128 + col8;
      if (wcol < M2LIM)
        *(short8*)(Ob + (size_t)(p0 + row) * PITCH2 + wcol) = *(const short8*)&OB[row * 136 + col8];
    }
  }
}

// ---- MFMA GEMM 64px x 128m (M=128) with fused epilogue, pipelined K-loop.
// MODE 3: Tr = acc + R; no LN (final ffc_out)
template<int MODE>
__global__ void __launch_bounds__(256) k_gemm64(const unsigned short* __restrict__ Wb,
                                                const unsigned short* __restrict__ Xg,
                                                const float* __restrict__ R,
                                                const float* __restrict__ Base,
                                                const float* __restrict__ gamma,
                                                const float* __restrict__ beta,
                                                float* __restrict__ Tr,
                                                unsigned short* __restrict__ LNo,
                                                int K, int PK){
  __shared__ short SMEM[8704];
  __shared__ float gls[128], bls[128];
  __shared__ float psum[64], pssq[64];
  short* Wls = SMEM;
  short* Xls = SMEM + 5120;
  int b  = blockIdx.z;
  int p0 = blockIdx.x * 64;
  int t  = threadIdx.x;
  int lanelo = t & 15;
  int quad   = (t >> 4) & 3;
  int wv = t >> 6;
  int w2 = wv >> 1, w1 = wv & 1;
  int srw = t >> 1;
  int kow = (t & 1) * 16;
  int srx = t >> 2;
  int kox = (t & 3) * 8;

  if (MODE != 3){
    if (t < 128){ gls[t] = gamma[t]; bls[t] = beta[t]; }
    if (t < 64){ psum[t] = 0.f; pssq[t] = 0.f; }
  }

  float4v acc[4][2];
  #pragma unroll
  for (int i = 0; i < 4; i++){
    acc[i][0] = (float4v){0.f, 0.f, 0.f, 0.f};
    acc[i][1] = (float4v){0.f, 0.f, 0.f, 0.f};
  }
  const unsigned short* Xp = Xg + (size_t)b * cP * PK + (size_t)(p0 + srx) * PK + kox;
  const unsigned short* Wp = Wb + (size_t)srw * K + kow;

  short8 xv  = *(const short8*)(Xp);
  short8 wv0 = *(const short8*)(Wp);
  short8 wv1 = *(const short8*)(Wp + 8);
  for (int k0 = 0; k0 < K; k0 += 32){
    __syncthreads();
    *(short8*)&Wls[srw * 40 + kow]     = wv0;
    *(short8*)&Wls[srw * 40 + kow + 8] = wv1;
    *(short8*)&Xls[srx * 40 + kox]     = xv;
    __syncthreads();
    if (k0 + 32 < K){
      xv  = *(const short8*)(Xp + k0 + 32);
      wv0 = *(const short8*)(Wp + k0 + 32);
      wv1 = *(const short8*)(Wp + k0 + 40);
    }
    short8 af[4], bfr[2];
    #pragma unroll
    for (int i = 0; i < 4; i++)
      af[i] = *(const short8*)&Wls[(w2 * 64 + i * 16 + lanelo) * 40 + quad * 8];
    #pragma unroll
    for (int j = 0; j < 2; j++)
      bfr[j] = *(const short8*)&Xls[(w1 * 32 + j * 16 + lanelo) * 40 + quad * 8];
    #pragma unroll
    for (int i = 0; i < 4; i++)
      #pragma unroll
      for (int j = 0; j < 2; j++)
        acc[i][j] = __builtin_amdgcn_mfma_f32_16x16x32_bf16(af[i], bfr[j], acc[i][j], 0, 0, 0);
  }
  float lnv[4][2][4];
  #pragma unroll
  for (int i = 0; i < 4; i++)
    #pragma unroll
    for (int j = 0; j < 2; j++){
      int n = p0 + w1 * 32 + j * 16 + lanelo;
      #pragma unroll
      for (int r = 0; r < 4; r++){
        int m = w2 * 64 + i * 16 + quad * 4 + r;
        size_t idx = (size_t)b * cC * cP + (size_t)m * cP + n;
        float v = acc[i][j][r];
        if (MODE >= 2) v += R[idx];
        Tr[idx] = v;
        if (MODE == 1) v += Base[idx];
        lnv[i][j][r] = v;
      }
    }
  if (MODE == 3) return;
  __syncthreads();
  #pragma unroll
  for (int j = 0; j < 2; j++){
    int nl = w1 * 32 + j * 16 + lanelo;
    float s = 0.f, ss = 0.f;
    #pragma unroll
    for (int i = 0; i < 4; i++)
      #pragma unroll
      for (int r = 0; r < 4; r++){
        float v = lnv[i][j][r];
        s += v; ss += v * v;
      }
    atomicAdd(&psum[nl], s);
    atomicAdd(&pssq[nl], ss);
  }
  __syncthreads();
  #pragma unroll
  for (int j = 0; j < 2; j++){
    int nl = w1 * 32 + j * 16 + lanelo;
    float mean = psum[nl] * (1.f / cC);
    float var = pssq[nl] * (1.f / cC) - mean * mean;
    float rstd = rsqrtf(var + cEPS);
    #pragma unroll
    for (int i = 0; i < 4; i++)
      #pragma unroll
      for (int r = 0; r < 4; r++){
        int m = w2 * 64 + i * 16 + quad * 4 + r;
        SMEM[nl * 136 + m] = (short)f2b((lnv[i][j][r] - mean) * rstd * gls[m] + bls[m]);
      }
  }
  __syncthreads();
  unsigned short* Ob = LNo + (size_t)b * cP * cC;
  #pragma unroll
  for (int rr = 0; rr < 4; rr++){
    int id = t + rr * 256;
    int row = id >> 4, col8 = (id & 15) * 8;
    short8 sv = *(const short8*)&SMEM[row * 136 + col8];
    *(short8*)(Ob + (size_t)(p0 + row) * cC + col8) = sv;
  }
}

// ---- depthwise 3x3 SAME, [p][c] layout, optional exact gelu ----
template<int GELU, int CCn, int PITCH>
__global__ void __launch_bounds__(256) k_dw(const unsigned short* __restrict__ in,
                                            const float* __restrict__ wt,
                                            unsigned short* __restrict__ out){
  __shared__ float wls[16 * 76];
  int t = threadIdx.x;
  int cbase = blockIdx.y * 128;
  for (int i = t; i < 16 * 72; i += 256){
    int cg = i / 72, rem = i - cg * 72;
    int tap = rem >> 3, j = rem & 7;
    int c = cbase + cg * 8 + j;
    wls[cg * 76 + rem] = (c < CCn) ? wt[c * 9 + tap] : 0.f;
  }
  __syncthreads();
  int cgl = t & 15, pixl = t >> 4;
  int c0 = cbase + cgl * 8;
  if (c0 >= PITCH) return;
  int p = blockIdx.x * 16 + pixl;
  int h = p >> 7, w = p & 127;
  int b = blockIdx.z;
  const unsigned short* ib = in + (size_t)b * cP * PITCH;
  float4 wreg[18];
  #pragma unroll
  for (int q = 0; q < 18; q++)
    wreg[q] = *(const float4*)&wls[cgl * 76 + q * 4];
  short8 v[9];
  #pragma unroll
  for (int ky = 0; ky < 3; ky++){
    int hh = h + ky - 1;
    bool okh = (unsigned)hh < (unsigned)cH;
    int hc = okh ? hh : h;
    #pragma unroll
    for (int kx = 0; kx < 3; kx++){
      int ww = w + kx - 1;
      bool okw = (unsigned)ww < (unsigned)cW;
      int wc = okw ? ww : w;
      short8 lv = *(const short8*)(ib + (size_t)(hc * cW + wc) * PITCH + c0);
      if (!(okh && okw)) lv = (short8){0,0,0,0,0,0,0,0};
      v[ky * 3 + kx] = lv;
    }
  }
  float acc[8] = {0,0,0,0,0,0,0,0};
  #pragma unroll
  for (int tap = 0; tap < 9; tap++){
    float4 w0 = wreg[tap * 2];
    float4 w1 = wreg[tap * 2 + 1];
    float wa[8] = {w0.x, w0.y, w0.z, w0.w, w1.x, w1.y, w1.z, w1.w};
    #pragma unroll
    for (int j = 0; j < 8; j++)
      acc[j] += wa[j] * bfu2f((unsigned short)v[tap][j]);
  }
  short8 ov;
  #pragma unroll
  for (int j = 0; j < 8; j++){
    float vv = acc[j];
    if (GELU) vv = 0.5f * vv * (1.f + erff(vv * 0.70710678118654752f));
    ov[j] = (short)f2b(vv);
  }
  *(short8*)(out + (size_t)b * cP * PITCH + (size_t)p * PITCH + c0) = ov;
}

// ---- fused depthwise-3x3 + RSA window attention ----
__global__ void __launch_bounds__(256) k_rsadw(const unsigned short* __restrict__ qkv,
                                               const float* __restrict__ wt,
                                               const float* __restrict__ temp,
                                               unsigned short* __restrict__ out){
  constexpr int QT = 0;
  constexpr int KT = 5120;
  constexpr int VO = 10240;
  constexpr int HA = 12416;
  constexpr int AT = 12416;
  __shared__ short lds[26528];
  __shared__ float nq[16], nk[16];
  int blk = blockIdx.x;
  int b  = blk >> 10;
  int nw = blk & 1023;
  int hb = nw >> 5, wb = nw & 31;
  int t = threadIdx.x;
  #pragma unroll
  for (int j = 0; j < 5; j++)
    *(short8*)&lds[t * 40 + j * 8] = (short8){0,0,0,0,0,0,0,0};
  if (t < 16) nq[t] = 0.f;
  else if (t < 32) nk[t - 16] = 0.f;
  __syncthreads();
  const unsigned short* base = qkv + (size_t)b * cP * cC3;
  #pragma unroll
  for (int r = 0; r < 7; r++){
    int i = t + 256 * r;
    if (i < 1728){
      int pix6 = i / 48;
      int cg = i - pix6 * 48;
      int hy = pix6 / 6, wx = pix6 - hy * 6;
      int hh = hb * 4 + hy - 1;
      int ww = wb * 4 + wx - 1;
      short8 v = (short8){0,0,0,0,0,0,0,0};
      if ((unsigned)hh < (unsigned)cH && (unsigned)ww < (unsigned)cW)
        v = *(const short8*)(base + (size_t)(hh * cW + ww) * cC3 + cg * 8);
      *(short8*)&lds[HA + pix6 * 392 + cg * 8] = v;
    }
  }
  __syncthreads();
  {
    int px = t & 15, grp = t >> 4;
    int py = px >> 2, pw = px & 3;
    #pragma unroll
    for (int g = 0; g < 3; g++){
      int c0 = grp * 24 + g * 8;
      const float4* wq = (const float4*)(wt + (size_t)c0 * 9);
      float wa[72];
      #pragma unroll
      for (int q = 0; q < 18; q++){
        float4 v4 = wq[q];
        wa[q * 4 + 0] = v4.x; wa[q * 4 + 1] = v4.y;
        wa[q * 4 + 2] = v4.z; wa[q * 4 + 3] = v4.w;
      }
      float acc8[8] = {0,0,0,0,0,0,0,0};
      #pragma unroll
      for (int ky = 0; ky < 3; ky++)
        #pragma unroll
        for (int kx = 0; kx < 3; kx++){
          short8 iv = *(const short8*)&lds[HA + ((py + ky) * 6 + pw + kx) * 392 + c0];
          int tap = ky * 3 + kx;
          #pragma unroll
          for (int e = 0; e < 8; e++)
            acc8[e] += wa[e * 9 + tap] * bfu2f((unsigned short)iv[e]);
        }
      if (c0 < 256){
        int isQ = c0 < 128;
        int off = isQ ? (QT + c0 * 40) : (KT + (c0 - 128) * 40);
        float s = 0.f;
        #pragma unroll
        for (int e = 0; e < 8; e++){
          unsigned short us = f2b(acc8[e]);
          float f = bfu2f(us);
          s += f * f;
          lds[off + e * 40 + px] = (short)us;
        }
        atomicAdd(isQ ? &nq[px] : &nk[px], s);
      } else {
        short8 sv;
        #pragma unroll
        for (int e = 0; e < 8; e++) sv[e] = (short)f2b(acc8[e]);
        *(short8*)&lds[VO + px * 136 + (c0 - 256)] = sv;
      }
    }
  }
  __syncthreads();
  float T = temp[0];
  #pragma unroll
  for (int r = 0; r < 8; r++){
    int idx = t + 256 * r;
    int c = idx >> 4, p = idx & 15;
    float sc = (1.f / fmaxf(sqrtf(nq[p]), 1e-12f)) * (1.f / fmaxf(sqrtf(nk[p]), 1e-12f));
    int a = QT + c * 40 + p;
    lds[a] = (short)f2b(bfu2f((unsigned short)lds[a]) * sc);
  }
  __syncthreads();
  int lanelo = t & 15;
  int quad = (t >> 4) & 3;
  int wv = t >> 6;
  float4v oacc[2];
  oacc[0] = (float4v){0.f,0.f,0.f,0.f};
  oacc[1] = (float4v){0.f,0.f,0.f,0.f};
  for (int ch = 0; ch < 2; ch++){
    #pragma unroll
    for (int ct = 0; ct < 4; ct++){
      int c0 = ch * 64 + ct * 16;
      short8 af = *(const short8*)&lds[QT + (c0 + lanelo) * 40 + quad * 8];
      #pragma unroll
      for (int dt = 0; dt < 2; dt++){
        int d0 = wv * 32 + dt * 16;
        short8 bf = *(const short8*)&lds[KT + (d0 + lanelo) * 40 + quad * 8];
        float4v acc = __builtin_amdgcn_mfma_f32_16x16x32_bf16(af, bf,
                        (float4v){0.f,0.f,0.f,0.f}, 0, 0, 0);
        short4v sv;
        #pragma unroll
        for (int r2 = 0; r2 < 4; r2++) sv[r2] = (short)f2b(fmaxf(acc[r2] * T, 0.f));
        *(short4v*)&lds[AT + (d0 + lanelo) * 72 + ct * 16 + quad * 4] = sv;
      }
    }
    __syncthreads();
    #pragma unroll
    for (int dt = 0; dt < 2; dt++){
      int d0 = wv * 32 + dt * 16;
      #pragma unroll
      for (int kk = 0; kk < 2; kk++){
        short8 av8 = *(const short8*)&lds[VO + lanelo * 136 + ch * 64 + kk * 32 + quad * 8];
        short8 bv8 = *(const short8*)&lds[AT + (d0 + lanelo) * 72 + kk * 32 + quad * 8];
        oacc[dt] = __builtin_amdgcn_mfma_f32_16x16x32_bf16(av8, bv8, oacc[dt], 0, 0, 0);
      }
    }
    __syncthreads();
  }
  #pragma unroll
  for (int dt = 0; dt < 2; dt++){
    int d = wv * 32 + dt * 16 + lanelo;
    #pragma unroll
    for (int r2 = 0; r2 < 4; r2++){
      int p = quad * 4 + r2;
      lds[p * 136 + d] = (short)f2b(oacc[dt][r2]);
    }
  }
  __syncthreads();
  {
    int px = t >> 4, cg = (t & 15) * 8;
    int h2 = (hb * 4 + (px >> 2) + 2) & (cH - 1);
    int w2 = (wb * 4 + (px & 3) + 2) & (cW - 1);
    short8 sv = *(const short8*)&lds[px * 136 + cg];
    *(short8*)(out + (size_t)b * cP * cC + (size_t)(h2 * cW + w2) * cC + cg) = sv;
  }
}

// ---- GSA Gram with on-the-fly depthwise-3x3 (Q,K channels of this head) ----
__global__ void __launch_bounds__(256) k_gramdw(const unsigned short* __restrict__ Ain,
                                                const float* __restrict__ dww,
                                                float* __restrict__ S,
                                                float* __restrict__ Qn,
                                                float* __restrict__ Kn){
  __shared__ float qs[32][132];
  __shared__ float ks[32][132];
  __shared__ float wdw[576];
  int blk = blockIdx.x;
  int chunk = blk & 127;
  int bh = blk >> 7;
  int b = bh >> 2, hd = bh & 3;
  int t = threadIdx.x;
  for (int i = t; i < 576; i += 256){
    int lc = i / 9, tpq = i - lc * 9;
    int c = (lc < 32) ? (hd * 32 + lc) : (128 + hd * 32 + (lc - 32));
    wdw[i] = dww[c * 9 + tpq];
  }
  __syncthreads();
  int row = t >> 1;
  int half = t & 1;
  int h = chunk, w = row;
  const unsigned short* Ab = Ain + (size_t)b * cP * cC3;
  float qa[16], ka[16];
  #pragma unroll
  for (int e = 0; e < 16; e++){ qa[e] = 0.f; ka[e] = 0.f; }
  #pragma unroll
  for (int ky = 0; ky < 3; ky++){
    int hh = h + ky - 1;
    if ((unsigned)hh >= (unsigned)cH) continue;
    #pragma unroll
    for (int kx = 0; kx < 3; kx++){
      int ww = w + kx - 1;
      if ((unsigned)ww >= (unsigned)cW) continue;
      const unsigned short* pp = Ab + (size_t)(hh * cW + ww) * cC3 + hd * 32 + half * 16;
      short8 q0 = *(const short8*)pp;
      short8 q1 = *(const short8*)(pp + 8);
      short8 k0v = *(const short8*)(pp + 128);
      short8 k1v = *(const short8*)(pp + 136);
      int tpi = ky * 3 + kx;
      #pragma unroll
      for (int e = 0; e < 8; e++){
        qa[e]     += wdw[(half * 16 + e) * 9 + tpi]          * bfu2f((unsigned short)q0[e]);
        qa[8 + e] += wdw[(half * 16 + 8 + e) * 9 + tpi]      * bfu2f((unsigned short)q1[e]);
        ka[e]     += wdw[(32 + half * 16 + e) * 9 + tpi]     * bfu2f((unsigned short)k0v[e]);
        ka[8 + e] += wdw[(32 + half * 16 + 8 + e) * 9 + tpi] * bfu2f((unsigned short)k1v[e]);
      }
    }
  }
  #pragma unroll
  for (int e = 0; e < 16; e++){
    qs[half * 16 + e][row] = bfu2f(f2b(qa[e]));
    ks[half * 16 + e][row] = bfu2f(f2b(ka[e]));
  }
  __syncthreads();
  if (t < 64){
    const float* rowp = (t < 32) ? qs[t] : ks[t - 32];
    float s = 0.f;
    #pragma unroll
    for (int i = 0; i < 128; i += 4){
      float4 v = *(const float4*)(rowp + i);
      s += v.x*v.x + v.y*v.y + v.z*v.z + v.w*v.w;
    }
    if (t < 32) atomicAdd(&Qn[bh * 32 + t], s);
    else        atomicAdd(&Kn[bh * 32 + (t - 32)], s);
  }
  int cc = (t >> 4) * 2;
  int dd = t & 15;
  float a00 = 0.f, a01 = 0.f, a10 = 0.f, a11 = 0.f;
  for (int n = 0; n < 128; n += 4){
    float4 q0 = *(const float4*)&qs[cc][n];
    float4 q1 = *(const float4*)&qs[cc + 1][n];
    float4 k0 = *(const float4*)&ks[dd][n];
    float4 k1 = *(const float4*)&ks[dd + 16][n];
    a00 += q0.x*k0.x + q0.y*k0.y + q0.z*k0.z + q0.w*k0.w;
    a01 += q0.x*k1.x + q0.y*k1.y + q0.z*k1.z + q0.w*k1.w;
    a10 += q1.x*k0.x + q1.y*k0.y + q1.z*k0.z + q1.w*k0.w;
    a11 += q1.x*k1.x + q1.y*k1.y + q1.z*k1.z + q1.w*k1.w;
  }
  float* Sb = S + (size_t)bh * 1024;
  atomicAdd(&Sb[cc * 32 + dd], a00);
  atomicAdd(&Sb[cc * 32 + dd + 16], a01);
  atomicAdd(&Sb[(cc + 1) * 32 + dd], a10);
  atomicAdd(&Sb[(cc + 1) * 32 + dd + 16], a11);
}

// ---- GSA apply via MFMA with on-the-fly depthwise-3x3 for V ----
__global__ void __launch_bounds__(256) k_applydw(const unsigned short* __restrict__ Ain,
                                                 const float* __restrict__ dww,
                                                 const float* __restrict__ S,
                                                 const float* __restrict__ Qn,
                                                 const float* __restrict__ Kn,
                                                 const float* __restrict__ temp,
                                                 unsigned short* __restrict__ out){
  __shared__ short atb[128 * 40];
  __shared__ short OT[64 * 136];
  __shared__ float wdw[1152];
  int b = blockIdx.y;
  int nbase = blockIdx.x * 64;
  int t = threadIdx.x;
  float T = temp[0];
  for (int i = t; i < 1152; i += 256)
    wdw[i] = dww[2304 + i];
  #pragma unroll
  for (int it = 0; it < 16; it++){
    int i = t + it * 256;
    int c = i >> 5, d = i & 31;
    int hd = c >> 5, cl = c & 31;
    int bh = b * 4 + hd;
    float nqv = fmaxf(sqrtf(Qn[bh * 32 + cl]), 1e-12f);
    float nkv = fmaxf(sqrtf(Kn[bh * 32 + d]), 1e-12f);
    float v = fmaxf(S[(size_t)bh * 1024 + cl * 32 + d] / (nqv * nkv) * T, 0.f);
    atb[c * 40 + d] = (short)f2b(v);
  }
  __syncthreads();
  int lanelo = t & 15, quad = (t >> 4) & 3, wv = t >> 6;
  int pix = nbase + wv * 16 + lanelo;
  int h = pix >> 7, w = pix & 127;
  const unsigned short* Ab = Ain + (size_t)b * cP * cC3;
  #pragma unroll
  for (int hd = 0; hd < 4; hd++){
    float va[8] = {0,0,0,0,0,0,0,0};
    #pragma unroll
    for (int ky = 0; ky < 3; ky++){
      int hh = h + ky - 1;
      if ((unsigned)hh >= (unsigned)cH) continue;
      #pragma unroll
      for (int kx = 0; kx < 3; kx++){
        int ww = w + kx - 1;
        if ((unsigned)ww >= (unsigned)cW) continue;
        short8 iv = *(const short8*)(Ab + (size_t)(hh * cW + ww) * cC3 + 256 + hd * 32 + quad * 8);
        int tpi = ky * 3 + kx;
        #pragma unroll
        for (int e = 0; e < 8; e++)
          va[e] += wdw[(hd * 32 + quad * 8 + e) * 9 + tpi] * bfu2f((unsigned short)iv[e]);
      }
    }
    short8 af;
    #pragma unroll
    for (int e = 0; e < 8; e++) af[e] = (short)f2b(va[e]);
    #pragma unroll
    for (int cth = 0; cth < 2; cth++){
      int c0 = hd * 32 + cth * 16;
      short8 bf = *(const short8*)&atb[(c0 + lanelo) * 40 + quad * 8];
      float4v acc = __builtin_amdgcn_mfma_f32_16x16x32_bf16(af, bf,
                      (float4v){0.f,0.f,0.f,0.f}, 0, 0, 0);
      #pragma unroll
      for (int r = 0; r < 4; r++)
        OT[(wv * 16 + quad * 4 + r) * 136 + c0 + lanelo] = (short)f2b(acc[r]);
    }
  }
  __syncthreads();
  unsigned short* ob = out + (size_t)b * cP * cC;
  #pragma unroll
  for (int rr = 0; rr < 4; rr++){
    int id = t + rr * 256;
    int row = id >> 4, col8 = (id & 15) * 8;
    *(short8*)(ob + (size_t)(nbase + row) * cC + col8) = *(const short8*)&OT[row * 136 + col8];
  }
}

extern "C" void kernel_launch(void* const* d_in, const int* in_sizes, int n_in,
                              void* d_out, int out_size, void* d_ws, size_t ws_size,
                              hipStream_t stream){
  const float* x     = (const float*)d_in[0];
  const float* w_s0  = (const float*)d_in[1];
  const float* b_s0  = (const float*)d_in[2];
  const float* w_s2  = (const float*)d_in[3];
  const float* b_s2  = (const float*)d_in[4];
  const float* rsa_qkv  = (const float*)d_in[5];
  const float* rsa_dw   = (const float*)d_in[6];
  const float* rsa_proj = (const float*)d_in[7];
  const float* rsa_temp = (const float*)d_in[8];
  const float* ffs_in   = (const float*)d_in[9];
  const float* ffs_dw   = (const float*)d_in[10];
  const float* ffs_out  = (const float*)d_in[11];
  const float* w_c0  = (const float*)d_in[12];
  const float* b_c0  = (const float*)d_in[13];
  const float* w_c2  = (const float*)d_in[14];
  const float* b_c2  = (const float*)d_in[15];
  const float* gsa_qkv  = (const float*)d_in[16];
  const float* gsa_dw   = (const float*)d_in[17];
  const float* gsa_proj = (const float*)d_in[18];
  const float* gsa_temp = (const float*)d_in[19];
  const float* ffc_in   = (const float*)d_in[20];
  const float* ffc_dw   = (const float*)d_in[21];
  const float* ffc_out  = (const float*)d_in[22];

  const size_t szC  = (size_t)cB * cC * cP;
  const size_t szC3 = (size_t)cB * cC3 * cP;
  float* XF = (float*)d_ws;
  float* XS = XF + szC;
  unsigned short* LO   = (unsigned short*)(XS + szC);
  unsigned short* Abuf = LO + szC;
  unsigned short* Bbuf = Abuf + szC3;
  float* S  = (float*)(Bbuf + szC3);
  float* Qn = S + 8192;
  float* Kn = Qn + 256;
  float* AT = Kn + 256;
  unsigned short* WB = (unsigned short*)(AT + 1024);
  unsigned short* W_QKV_S = WB;
  unsigned short* W_QKV_C = WB + 49152;
  unsigned short* W_FIN_S = WB + 98304;
  unsigned short* W_FIN_C = WB + 147456;
  unsigned short* W_PRJ_S = WB + 196608;
  unsigned short* W_PRJ_C = WB + 212992;
  unsigned short* W_FO_S  = WB + 229376;
  unsigned short* W_FO_C  = WB + 274432;

  dim3 t256(256);
  dim3 gG1(cP / 64 * 3 * cB);
  dim3 gG64(cP / 64, 1, cB);
  dim3 gDW(cP / 16, 3, cB);

  k_wcvt<<<dim3(1282), t256, 0, stream>>>(rsa_qkv, gsa_qkv, ffs_in, ffc_in,
                                          rsa_proj, gsa_proj, ffs_out, ffc_out, WB, S);

  // ---------------- spatial (RSA) block ----------------
  k_gemmLN<<<gG1, t256, 0, stream>>>(W_QKV_S, x, w_s0, b_s0, Abuf);
  k_rsadw<<<dim3(cB * cNW), t256, 0, stream>>>(Abuf, rsa_dw, rsa_temp, LO);
  // PRJ_S + LN(w_s2) + FIN_S fused
  k_gfuse<1><<<gG64, t256, 0, stream>>>(W_PRJ_S, LO, nullptr, x, w_s2, b_s2, XS,
                                        W_FIN_S, Abuf, 128, 128, 352, 352);
  k_dw<1,340,352><<<gDW, t256, 0, stream>>>(Abuf, ffs_dw, Bbuf);
  // FO_S + residual(XS) + LN(w_c0) + QKV_C fused
  k_gfuse<2><<<gG64, t256, 0, stream>>>(W_FO_S, Bbuf, XS, nullptr, w_c0, b_c0, XF,
                                        W_QKV_C, Abuf, 352, 352, 384, 384);

  // ---------------- channel (GSA) block ----------------
  k_gramdw<<<dim3(1024), t256, 0, stream>>>(Abuf, gsa_dw, S, Qn, Kn);
  k_applydw<<<dim3(cP / 64, cB), t256, 0, stream>>>(Abuf, gsa_dw, S, Qn, Kn, gsa_temp, LO);
  // PRJ_C + LN(w_c2) + FIN_C fused
  k_gfuse<1><<<gG64, t256, 0, stream>>>(W_PRJ_C, LO, nullptr, XF, w_c2, b_c2, XS,
                                        W_FIN_C, Abuf, 128, 128, 352, 352);
  k_dw<1,340,352><<<gDW, t256, 0, stream>>>(Abuf, ffc_dw, Bbuf);
  k_gemm64<3><<<gG64, t256, 0, stream>>>(W_FO_C, Bbuf, XS, nullptr, nullptr, nullptr,
                                         (float*)d_out, nullptr, 352, 352);
}